// Round 4
// baseline (670.289 us; speedup 1.0000x reference)
//
#include <hip/hip_runtime.h>
#include <math.h>
#include <stdint.h>

// ScalarSGC: 2 layers of  x <- elu( scalars[l] * (A @ x) )
// CSR build: DIRECT single-scatter with global cursor atomics.
//   count (atomicAdd per edge) -> scan (tile scan + tile-sum scan + add-base)
//   -> scatter edges straight into final row-grouped pack[] positions.
// 3.2M int atomics on 100K addresses are cheap; this deletes the old
// partition + fine_sort double-scatter (saved ~100MB of traffic + 2 big
// LDS-scan kernels).
// SpMM: 16-lane GROUP per row; lane owns 16B (8 bf16 features) of the row.
// Wave = 4 groups -> one gather instruction moves 4 x 256B = 1KB.

#define D_FEAT 128
#define D2     64          // feature pairs per row
#define SCAN_TILE 1024

__device__ __forceinline__ uint32_t f2bf(float f) {
    uint32_t u = __float_as_uint(f);
    return (u + 0x7FFFu + ((u >> 16) & 1u)) >> 16;   // RNE
}
__device__ __forceinline__ float bf_lo(uint32_t w) { return __uint_as_float(w << 16); }
__device__ __forceinline__ float bf_hi(uint32_t w) { return __uint_as_float(w & 0xFFFF0000u); }

// ---------------- f32 -> bf16 conversion (2 elems/thread) ----------------
__global__ void convert_kernel(const float2* __restrict__ xin, uint32_t* __restrict__ xbf, int n2) {
    int i = blockIdx.x * blockDim.x + threadIdx.x;
    if (i < n2) {
        float2 f = xin[i];
        xbf[i] = f2bf(f.x) | (f2bf(f.y) << 16);
    }
}

// ---------------- per-row degree count (global atomics) ----------------
__global__ __launch_bounds__(256) void count_kernel(const int* __restrict__ row,
                                                    int* __restrict__ cnt, int E) {
    int i = blockIdx.x * 256 + threadIdx.x;
    if (i < E) atomicAdd(&cnt[row[i]], 1);
}

// ---------------- scan phase 1: per-tile exclusive scan + tile sums ----------------
__global__ __launch_bounds__(SCAN_TILE) void scan1_kernel(const int* __restrict__ counts,
                                                          int* __restrict__ excl,
                                                          int* __restrict__ tileSums, int n) {
    __shared__ int wsum[16];
    const int tid  = threadIdx.x;
    const int lane = tid & 63;
    const int wave = tid >> 6;
    const int i    = blockIdx.x * SCAN_TILE + tid;

    int v = (i < n) ? counts[i] : 0;
    int incl = v;
    #pragma unroll
    for (int off = 1; off < 64; off <<= 1) {
        int t = __shfl_up(incl, off, 64);
        if (lane >= off) incl += t;
    }
    if (lane == 63) wsum[wave] = incl;
    __syncthreads();
    if (wave == 0) {
        int s = (lane < 16) ? wsum[lane] : 0;
        #pragma unroll
        for (int off = 1; off < 16; off <<= 1) {
            int t = __shfl_up(s, off, 64);
            if (lane >= off) s += t;
        }
        if (lane < 16) wsum[lane] = s;
    }
    __syncthreads();
    int wbase = (wave == 0) ? 0 : wsum[wave - 1];
    if (i < n) excl[i] = wbase + (incl - v);
    if (tid == 0) tileSums[blockIdx.x] = wsum[15];
}

// ---------------- scan phase 2: scan tile sums (single block) ----------------
__global__ __launch_bounds__(1024) void scan2_kernel(const int* __restrict__ tileSums,
                                                     int* __restrict__ tileBase,
                                                     int* __restrict__ total_out, int nb) {
    __shared__ int buf[1024];
    const int tid = threadIdx.x;
    int v = (tid < nb) ? tileSums[tid] : 0;
    buf[tid] = v;
    __syncthreads();
    #pragma unroll
    for (int off = 1; off < 1024; off <<= 1) {
        int t = (tid >= off) ? buf[tid - off] : 0;
        __syncthreads();
        buf[tid] += t;
        __syncthreads();
    }
    if (tid < nb) tileBase[tid] = buf[tid] - v;
    if (tid == nb - 1) *total_out = buf[tid];
}

// ---------------- add tile base: final offsets + scatter cursors ----------------
__global__ __launch_bounds__(256) void add_base_kernel(const int* __restrict__ excl,
                                                       const int* __restrict__ tileBase,
                                                       int* __restrict__ offsets,
                                                       int* __restrict__ cur, int N, int E) {
    int i = blockIdx.x * 256 + threadIdx.x;
    if (i < N) {
        int v = excl[i] + tileBase[i >> 10];
        offsets[i] = v;
        cur[i] = v;
    }
    if (i == 0) offsets[N] = E;
}

// ---------------- direct scatter into final row-grouped positions ----------------
__global__ __launch_bounds__(256) void scatter_kernel(const int* __restrict__ row,
                                                      const int* __restrict__ col,
                                                      const float* __restrict__ val,
                                                      int* __restrict__ cur,
                                                      int2* __restrict__ pack, int E) {
    int i = blockIdx.x * 256 + threadIdx.x;
    if (i < E) {
        int r = row[i];
        int pos = atomicAdd(&cur[r], 1);             // global cursor atomic
        pack[pos] = make_int2(col[i], __float_as_int(val[i]));
    }
}

// ---------------- fused SpMM (bf16 gather) + scalar scale + ELU ----------------
// Block = 256 threads = 16 groups of 16 lanes; GROUP owns one row.  Lane owns
// 16B (4 bf16-pair words = 8 features) of that row's accumulator.  A wave's
// gather instruction covers 4 groups x 256B = 1KB.  pack[] reads are
// group-uniform (HW broadcast).  No cross-lane reduction, no selection logic.
template <int OUT_BF16>
__global__ __launch_bounds__(256) void spmm_elu_kernel(
    const int* __restrict__ offsets, const int2* __restrict__ pack,
    const uint32_t* __restrict__ xin, void* __restrict__ xout,
    const float* __restrict__ scalars, int layer, int N) {
    const int tid = threadIdx.x;
    const int grp = tid >> 4;            // group within block (0..15)
    const int sub = tid & 15;            // 16B chunk within the source row
    const int r   = blockIdx.x * 16 + grp;

    int e = 0, end = 0;
    if (r < N) { e = offsets[r]; end = offsets[r + 1]; }

    const uint4* __restrict__ xin4 = (const uint4*)xin;   // row stride = 16 uint4

    float a[8];
    #pragma unroll
    for (int k = 0; k < 8; ++k) a[k] = 0.f;

    #define FMA8(W, V)                                                     \
        a[0] += (V) * bf_lo((W).x); a[1] += (V) * bf_hi((W).x);            \
        a[2] += (V) * bf_lo((W).y); a[3] += (V) * bf_hi((W).y);            \
        a[4] += (V) * bf_lo((W).z); a[5] += (V) * bf_hi((W).z);            \
        a[6] += (V) * bf_lo((W).w); a[7] += (V) * bf_hi((W).w);

    for (; e + 4 <= end; e += 4) {
        int2 p0 = pack[e], p1 = pack[e + 1], p2 = pack[e + 2], p3 = pack[e + 3];
        uint4 w0 = xin4[(((uint32_t)p0.x) << 4) + sub];
        uint4 w1 = xin4[(((uint32_t)p1.x) << 4) + sub];
        uint4 w2 = xin4[(((uint32_t)p2.x) << 4) + sub];
        uint4 w3 = xin4[(((uint32_t)p3.x) << 4) + sub];
        FMA8(w0, __int_as_float(p0.y));
        FMA8(w1, __int_as_float(p1.y));
        FMA8(w2, __int_as_float(p2.y));
        FMA8(w3, __int_as_float(p3.y));
    }
    for (; e < end; ++e) {
        int2 p = pack[e];
        uint4 w = xin4[(((uint32_t)p.x) << 4) + sub];
        FMA8(w, __int_as_float(p.y));
    }
    #undef FMA8

    const float s = scalars[layer];
    #pragma unroll
    for (int k = 0; k < 8; ++k) {
        float x = a[k] * s;
        a[k] = (x > 0.f) ? x : (expf(x) - 1.f);
    }

    if (r < N) {
        if (OUT_BF16) {
            uint4 o;
            o.x = f2bf(a[0]) | (f2bf(a[1]) << 16);
            o.y = f2bf(a[2]) | (f2bf(a[3]) << 16);
            o.z = f2bf(a[4]) | (f2bf(a[5]) << 16);
            o.w = f2bf(a[6]) | (f2bf(a[7]) << 16);
            ((uint4*)xout)[(size_t)r * 16 + sub] = o;
        } else {
            ((float4*)xout)[(size_t)r * 32 + sub * 2]     = make_float4(a[0], a[1], a[2], a[3]);
            ((float4*)xout)[(size_t)r * 32 + sub * 2 + 1] = make_float4(a[4], a[5], a[6], a[7]);
        }
    }
}

extern "C" void kernel_launch(void* const* d_in, const int* in_sizes, int n_in,
                              void* d_out, int out_size, void* d_ws, size_t ws_size,
                              hipStream_t stream) {
    const float* x         = (const float*)d_in[0];
    const int*   edge_row  = (const int*)d_in[1];
    const int*   edge_col  = (const int*)d_in[2];
    const float* edge_vals = (const float*)d_in[3];
    const float* scalars   = (const float*)d_in[4];

    const int N = in_sizes[0] / D_FEAT;                      // 100000
    const int E = in_sizes[1];                               // 3200000
    const int NB = (N + SCAN_TILE - 1) / SCAN_TILE;          // 98

    // ---- workspace bump allocator (256B aligned) ----
    char*  ws  = (char*)d_ws;
    size_t off = 0;
    auto alloc = [&](size_t bytes) -> void* {
        off = (off + 255) & ~(size_t)255;
        void* p = ws + off;
        off += bytes;
        return p;
    };
    int*      offsets  = (int*)alloc((size_t)(N + 1) * sizeof(int));
    int*      cnt      = (int*)alloc((size_t)N * sizeof(int));       // degree -> excl (in place)
    int*      cur      = (int*)alloc((size_t)N * sizeof(int));       // scatter cursors
    int*      tileSums = (int*)alloc((size_t)(NB + 1) * sizeof(int));
    int*      tileBase = (int*)alloc((size_t)NB * sizeof(int));
    int2*     pack     = (int2*)alloc((size_t)E * sizeof(int2));
    uint32_t* xbf      = (uint32_t*)alloc((size_t)N * D2 * sizeof(uint32_t));
    uint32_t* hbf      = (uint32_t*)alloc((size_t)N * D2 * sizeof(uint32_t));
    (void)ws_size;

    // ---- CSR build: count -> scan -> direct scatter ----
    hipMemsetAsync(cnt, 0, (size_t)N * sizeof(int), stream);
    convert_kernel<<<(N * D2 + 255) / 256, 256, 0, stream>>>((const float2*)x, xbf, N * D2);
    count_kernel<<<(E + 255) / 256, 256, 0, stream>>>(edge_row, cnt, E);
    scan1_kernel<<<NB, SCAN_TILE, 0, stream>>>(cnt, cnt, tileSums, N);
    scan2_kernel<<<1, 1024, 0, stream>>>(tileSums, tileBase, tileSums + NB, NB);
    add_base_kernel<<<(N + 255) / 256, 256, 0, stream>>>(cnt, tileBase, offsets, cur, N, E);
    scatter_kernel<<<(E + 255) / 256, 256, 0, stream>>>(edge_row, edge_col, edge_vals,
                                                        cur, pack, E);

    // ---- layer 1: xbf -> hbf (bf16), layer 2: hbf -> d_out (f32) ----
    const int nblk = (N + 15) / 16;
    spmm_elu_kernel<1><<<nblk, 256, 0, stream>>>(offsets, pack, xbf, hbf, scalars, 0, N);
    spmm_elu_kernel<0><<<nblk, 256, 0, stream>>>(offsets, pack, hbf, (void*)d_out, scalars, 1, N);
}

// Round 5
// 427.065 us; speedup vs baseline: 1.5695x; 1.5695x over previous
//
#include <hip/hip_runtime.h>
#include <math.h>
#include <stdint.h>

// ScalarSGC: 2 layers of  x <- elu( scalars[l] * (A @ x) )
// CSR build (bucketed, zero global atomics -- R4 showed direct random scatter
// is 7.7x write-amplified and latency-serialized):
//   fused convert+coarse-count -> tile scan -> wave scan -> partition into
//   196 buckets (sequential write streams per block) -> lean per-bucket fine
//   sort (no LDS edge cache: bucket is L2-resident; wave-shuffle scan, 4
//   barriers instead of ~21).
// SpMM: 16-lane GROUP per row; lane owns 16B (8 bf16 features) of the row.
// Wave = 4 groups -> one gather instruction moves 4 x 256B = 1KB.

#define D_FEAT 128
#define D2     64          // feature pairs per row
#define SCAN_TILE 1024

#define PB 256             // partition/count blocks (= gridDim of those kernels)
#define PT 1024            // threads per partition/count block
#define RB_BITS 9          // rows per bucket = 512
#define ROWS_PER_BUCKET 512
#define COL_BITS 17        // N = 100000 < 2^17

__device__ __forceinline__ uint32_t f2bf(float f) {
    uint32_t u = __float_as_uint(f);
    return (u + 0x7FFFu + ((u >> 16) & 1u)) >> 16;   // RNE
}
__device__ __forceinline__ float bf_lo(uint32_t w) { return __uint_as_float(w << 16); }
__device__ __forceinline__ float bf_hi(uint32_t w) { return __uint_as_float(w & 0xFFFF0000u); }

// ------- fused: f32 -> bf16 table convert (float4) + coarse bucket count -------
__global__ __launch_bounds__(PT) void convert_count_kernel(const float4* __restrict__ xin,
                                                           uint2* __restrict__ xbf, int n4,
                                                           const int* __restrict__ row,
                                                           int* __restrict__ cnt,
                                                           int E, int nbuck) {
    __shared__ int hist[256];
    const int t = threadIdx.x;
    if (t < 256) hist[t] = 0;
    __syncthreads();
    const int stride = PB * PT;
    const int gid = blockIdx.x * PT + t;
    for (int i = gid; i < n4; i += stride) {
        float4 f = xin[i];
        xbf[i] = make_uint2(f2bf(f.x) | (f2bf(f.y) << 16),
                            f2bf(f.z) | (f2bf(f.w) << 16));
    }
    for (int i = gid; i < E; i += stride)
        atomicAdd(&hist[row[i] >> RB_BITS], 1);
    __syncthreads();
    if (t < nbuck) cnt[t * PB + blockIdx.x] = hist[t];
}

// ---------------- scan phase 1: per-tile exclusive scan + tile sums ----------------
__global__ __launch_bounds__(SCAN_TILE) void scan1_kernel(const int* __restrict__ counts,
                                                          int* __restrict__ excl,
                                                          int* __restrict__ tileSums, int n) {
    __shared__ int wsum[16];
    const int tid  = threadIdx.x;
    const int lane = tid & 63;
    const int wave = tid >> 6;
    const int i    = blockIdx.x * SCAN_TILE + tid;

    int v = (i < n) ? counts[i] : 0;
    int incl = v;
    #pragma unroll
    for (int off = 1; off < 64; off <<= 1) {
        int t = __shfl_up(incl, off, 64);
        if (lane >= off) incl += t;
    }
    if (lane == 63) wsum[wave] = incl;
    __syncthreads();
    if (wave == 0) {
        int s = (lane < 16) ? wsum[lane] : 0;
        #pragma unroll
        for (int off = 1; off < 16; off <<= 1) {
            int t = __shfl_up(s, off, 64);
            if (lane >= off) s += t;
        }
        if (lane < 16) wsum[lane] = s;
    }
    __syncthreads();
    int wbase = (wave == 0) ? 0 : wsum[wave - 1];
    if (i < n) excl[i] = wbase + (incl - v);
    if (tid == 0) tileSums[blockIdx.x] = wsum[15];
}

// ---------------- scan phase 2: single-wave shuffle scan of tile sums ----------------
__global__ __launch_bounds__(64) void scan2_kernel(const int* __restrict__ tileSums,
                                                   int* __restrict__ tileBase,
                                                   int* __restrict__ total_out, int nb) {
    const int lane = threadIdx.x;
    int v = (lane < nb) ? tileSums[lane] : 0;
    int incl = v;
    #pragma unroll
    for (int off = 1; off < 64; off <<= 1) {
        int t = __shfl_up(incl, off, 64);
        if (lane >= off) incl += t;
    }
    if (lane < nb) tileBase[lane] = incl - v;
    if (lane == nb - 1) *total_out = incl;
}

// ---------------- partition edges into coarse buckets (LDS cursors) ----------------
// 196 concurrent sequential write streams per block -> line-aggregated stores.
__global__ __launch_bounds__(PT) void partition_kernel(const int* __restrict__ row,
                                                       const int* __restrict__ col,
                                                       const float* __restrict__ val,
                                                       const int* __restrict__ cnt,
                                                       const int* __restrict__ tileBase,
                                                       int2* __restrict__ pack2,
                                                       int E, int nbuck) {
    __shared__ int cur[256];
    const int t = threadIdx.x;
    if (t < nbuck) {
        int idx = t * PB + blockIdx.x;
        cur[t] = cnt[idx] + tileBase[idx >> 10];
    }
    __syncthreads();
    const int stride = PB * PT;
    for (int i = blockIdx.x * PT + t; i < E; i += stride) {
        int r = row[i];
        int pos = atomicAdd(&cur[r >> RB_BITS], 1);   // LDS atomic
        pack2[pos] = make_int2(col[i] | ((r & (ROWS_PER_BUCKET - 1)) << COL_BITS),
                               __float_as_int(val[i]));
    }
}

// ---------------- lean per-bucket fine sort ----------------
// No LDS edge cache (bucket ~131KB is L2-resident; re-read is cheap).
// 512-bin histogram + wave-shuffle scan: 4 barriers total, ~6KB LDS.
__global__ __launch_bounds__(1024) void fine_sort_kernel(const int* __restrict__ cnt,
                                                         const int* __restrict__ tileBase,
                                                         const int2* __restrict__ pack2,
                                                         int2* __restrict__ pack,
                                                         int* __restrict__ offsets,
                                                         int E, int N, int nbuck) {
    __shared__ int hist[ROWS_PER_BUCKET];
    __shared__ int cur[ROWS_PER_BUCKET];
    __shared__ int wsum[8];
    const int b    = blockIdx.x;
    const int t    = threadIdx.x;
    const int wave = t >> 6;
    const int lane = t & 63;
    const int start = cnt[b << 8] + tileBase[b >> 2];
    const int end   = (b == nbuck - 1) ? E : (cnt[(b + 1) << 8] + tileBase[(b + 1) >> 2]);
    const int n = end - start;

    if (t < ROWS_PER_BUCKET) hist[t] = 0;
    __syncthreads();

    for (int i = t; i < n; i += 1024)
        atomicAdd(&hist[((unsigned)pack2[start + i].x) >> COL_BITS], 1);
    __syncthreads();

    int v = 0, incl = 0;
    if (t < ROWS_PER_BUCKET) {           // waves 0..7, whole waves only
        v = hist[t];
        incl = v;
        #pragma unroll
        for (int off = 1; off < 64; off <<= 1) {
            int tv = __shfl_up(incl, off, 64);
            if (lane >= off) incl += tv;
        }
        if (lane == 63) wsum[wave] = incl;
    }
    __syncthreads();
    if (wave == 0) {                     // scan 8 wave sums
        int s = (lane < 8) ? wsum[lane] : 0;
        #pragma unroll
        for (int off = 1; off < 8; off <<= 1) {
            int tv = __shfl_up(s, off, 64);
            if (lane >= off) s += tv;
        }
        if (lane < 8) wsum[lane] = s;    // inclusive
    }
    __syncthreads();
    if (t < ROWS_PER_BUCKET) {
        int base = (wave == 0) ? 0 : wsum[wave - 1];
        int excl = base + incl - v;
        cur[t] = excl;
        int r = (b << RB_BITS) + t;
        if (r < N) offsets[r] = start + excl;
    }
    if (b == 0 && t == 0) offsets[N] = E;
    __syncthreads();

    for (int i = t; i < n; i += 1024) {
        int2 w = pack2[start + i];
        int lr = ((unsigned)w.x) >> COL_BITS;
        int p = atomicAdd(&cur[lr], 1);               // LDS atomic
        pack[start + p] = make_int2(w.x & ((1 << COL_BITS) - 1), w.y);
    }
}

// ---------------- fused SpMM (bf16 gather) + scalar scale + ELU ----------------
// Block = 256 threads = 16 groups of 16 lanes; GROUP owns one row.  Lane owns
// 16B (4 bf16-pair words = 8 features) of that row's accumulator.  A wave's
// gather instruction covers 4 groups x 256B = 1KB.  pack[] reads are
// group-uniform (HW broadcast).  No cross-lane reduction, no selection logic.
template <int OUT_BF16>
__global__ __launch_bounds__(256) void spmm_elu_kernel(
    const int* __restrict__ offsets, const int2* __restrict__ pack,
    const uint32_t* __restrict__ xin, void* __restrict__ xout,
    const float* __restrict__ scalars, int layer, int N) {
    const int tid = threadIdx.x;
    const int grp = tid >> 4;            // group within block (0..15)
    const int sub = tid & 15;            // 16B chunk within the source row
    const int r   = blockIdx.x * 16 + grp;

    int e = 0, end = 0;
    if (r < N) { e = offsets[r]; end = offsets[r + 1]; }

    const uint4* __restrict__ xin4 = (const uint4*)xin;   // row stride = 16 uint4

    float a[8];
    #pragma unroll
    for (int k = 0; k < 8; ++k) a[k] = 0.f;

    #define FMA8(W, V)                                                     \
        a[0] += (V) * bf_lo((W).x); a[1] += (V) * bf_hi((W).x);            \
        a[2] += (V) * bf_lo((W).y); a[3] += (V) * bf_hi((W).y);            \
        a[4] += (V) * bf_lo((W).z); a[5] += (V) * bf_hi((W).z);            \
        a[6] += (V) * bf_lo((W).w); a[7] += (V) * bf_hi((W).w);

    for (; e + 4 <= end; e += 4) {
        int2 p0 = pack[e], p1 = pack[e + 1], p2 = pack[e + 2], p3 = pack[e + 3];
        uint4 w0 = xin4[(((uint32_t)p0.x) << 4) + sub];
        uint4 w1 = xin4[(((uint32_t)p1.x) << 4) + sub];
        uint4 w2 = xin4[(((uint32_t)p2.x) << 4) + sub];
        uint4 w3 = xin4[(((uint32_t)p3.x) << 4) + sub];
        FMA8(w0, __int_as_float(p0.y));
        FMA8(w1, __int_as_float(p1.y));
        FMA8(w2, __int_as_float(p2.y));
        FMA8(w3, __int_as_float(p3.y));
    }
    for (; e < end; ++e) {
        int2 p = pack[e];
        uint4 w = xin4[(((uint32_t)p.x) << 4) + sub];
        FMA8(w, __int_as_float(p.y));
    }
    #undef FMA8

    const float s = scalars[layer];
    #pragma unroll
    for (int k = 0; k < 8; ++k) {
        float x = a[k] * s;
        a[k] = (x > 0.f) ? x : (expf(x) - 1.f);
    }

    if (r < N) {
        if (OUT_BF16) {
            uint4 o;
            o.x = f2bf(a[0]) | (f2bf(a[1]) << 16);
            o.y = f2bf(a[2]) | (f2bf(a[3]) << 16);
            o.z = f2bf(a[4]) | (f2bf(a[5]) << 16);
            o.w = f2bf(a[6]) | (f2bf(a[7]) << 16);
            ((uint4*)xout)[(size_t)r * 16 + sub] = o;
        } else {
            ((float4*)xout)[(size_t)r * 32 + sub * 2]     = make_float4(a[0], a[1], a[2], a[3]);
            ((float4*)xout)[(size_t)r * 32 + sub * 2 + 1] = make_float4(a[4], a[5], a[6], a[7]);
        }
    }
}

extern "C" void kernel_launch(void* const* d_in, const int* in_sizes, int n_in,
                              void* d_out, int out_size, void* d_ws, size_t ws_size,
                              hipStream_t stream) {
    const float* x         = (const float*)d_in[0];
    const int*   edge_row  = (const int*)d_in[1];
    const int*   edge_col  = (const int*)d_in[2];
    const float* edge_vals = (const float*)d_in[3];
    const float* scalars   = (const float*)d_in[4];

    const int N = in_sizes[0] / D_FEAT;                      // 100000
    const int E = in_sizes[1];                               // 3200000
    const int nbuck = (N + ROWS_PER_BUCKET - 1) >> RB_BITS;  // 196
    const int M = nbuck * PB;                                // 50176
    const int NB = (M + SCAN_TILE - 1) / SCAN_TILE;          // 49

    // ---- workspace bump allocator (256B aligned) ----
    char*  ws  = (char*)d_ws;
    size_t off = 0;
    auto alloc = [&](size_t bytes) -> void* {
        off = (off + 255) & ~(size_t)255;
        void* p = ws + off;
        off += bytes;
        return p;
    };
    int*      offsets  = (int*)alloc((size_t)(N + 1) * sizeof(int));
    int*      cnt      = (int*)alloc((size_t)(M + 1) * sizeof(int));
    int*      tileSums = (int*)alloc((size_t)NB * sizeof(int));
    int*      tileBase = (int*)alloc((size_t)NB * sizeof(int));
    int2*     pack2    = (int2*)alloc((size_t)E * sizeof(int2));
    int2*     pack     = (int2*)alloc((size_t)E * sizeof(int2));
    uint32_t* xbf      = (uint32_t*)alloc((size_t)N * D2 * sizeof(uint32_t));
    uint32_t* hbf      = (uint32_t*)pack2;   // alias: pack2 dead after fine_sort
    (void)ws_size;

    // ---- bf16 table + CSR build (no global atomics) ----
    convert_count_kernel<<<PB, PT, 0, stream>>>((const float4*)x, (uint2*)xbf, N * D2 / 2,
                                                edge_row, cnt, E, nbuck);
    scan1_kernel<<<NB, SCAN_TILE, 0, stream>>>(cnt, cnt, tileSums, M);
    scan2_kernel<<<1, 64, 0, stream>>>(tileSums, tileBase, cnt + M, NB);
    partition_kernel<<<PB, PT, 0, stream>>>(edge_row, edge_col, edge_vals, cnt, tileBase,
                                            pack2, E, nbuck);
    fine_sort_kernel<<<nbuck, 1024, 0, stream>>>(cnt, tileBase, pack2, pack, offsets, E, N, nbuck);

    // ---- layer 1: xbf -> hbf (bf16), layer 2: hbf -> d_out (f32) ----
    const int nblk = (N + 15) / 16;
    spmm_elu_kernel<1><<<nblk, 256, 0, stream>>>(offsets, pack, xbf, hbf, scalars, 0, N);
    spmm_elu_kernel<0><<<nblk, 256, 0, stream>>>(offsets, pack, hbf, (void*)d_out, scalars, 1, N);
}